// Round 9
// baseline (316.126 us; speedup 1.0000x reference)
//
#include <hip/hip_runtime.h>
#include <math.h>

#define Bn 4
#define Nn 512
#define Dn 64
#define Hn 8
#define TR 64          // rows per tile
#define NP 4           // tile-pairs per (b,q): each block streams 2 tiles
#define PS 68          // ehat row stride (words); 8 heads -> distinct banks
#define PART 80        // partial floats per block: 64 PV + 8 expsum + 8 gsum

typedef float f32x4 __attribute__((ext_vector_type(4)));

// ---------------- Kernel 1: QKV projection -------------------------------
__global__ __launch_bounds__(64) void qkv_kernel(
    const float* __restrict__ nin, const float* __restrict__ Wq,
    const float* __restrict__ Wk, const float* __restrict__ Wv,
    float* __restrict__ Qw, float* __restrict__ Kw, float* __restrict__ Vw)
{
    const int row = blockIdx.x;   // 0 .. B*N-1
    const int d = threadIdx.x;    // 0 .. 63
    __shared__ float nrow[Dn];
    nrow[d] = nin[row * Dn + d];
    __syncthreads();
    float aq = 0.f, ak = 0.f, av = 0.f;
#pragma unroll
    for (int k = 0; k < Dn; ++k) {
        const float nv = nrow[k];
        aq = fmaf(nv, Wq[k * Dn + d], aq);
        ak = fmaf(nv, Wk[k * Dn + d], ak);
        av = fmaf(nv, Wv[k * Dn + d], av);
    }
    Qw[row * Dn + d] = aq;
    Kw[row * Dn + d] = ak;
    Vw[row * Dn + d] = av;
}

// ---------------- Kernel 2: pipelined streaming tile kernel ---------------
// One block per (b,q,tile-pair): two 64-row tiles, software-pipelined.
// Per tile: [A] staged regs -> swizzled LDS, [bar1], [B] issue NEXT tile's
// coalesced 16KB loads (fly under compute), [C] eb/gg dots (lane=row, wave=
// head-pair) + A_qk + ehat -> LDS + exp/gate wave-reduce, [bar2], [D] e_out
// per-output-chunk nt stores + PV accumulate in regs. Partials written once.
__global__ __launch_bounds__(256, 6) void stream_kernel(
    const float* __restrict__ e,
    const float* __restrict__ Qw, const float* __restrict__ Kw,
    const float* __restrict__ Vw,
    const float* __restrict__ WeG, const float* __restrict__ WgG,
    const float* __restrict__ OeG,
    float* __restrict__ eout, float* __restrict__ part)
{
    const int bid = blockIdx.x;        // bq*NP + tp
    const int bq  = bid >> 2;          // NP = 4
    const int tp  = bid & 3;
    const int b   = bq >> 9;           // N = 512
    const int t   = threadIdx.x;       // 0..255
    const int w   = t >> 6;            // wave 0..3 = head-pair {2w,2w+1}
    const int l   = t & 63;            // lane = row within tile (phase C)

    __shared__ float e_tile[TR * Dn];               // 16384 B, swizzled
    __shared__ float ehat_s[Hn * PS];               // 2176 B
    __shared__ __align__(16) float we_s[Hn][Dn];    // 2048 B
    __shared__ __align__(16) float wg_s[Hn][Dn];    // 2048 B
    __shared__ __align__(16) float oe_s[Hn][Dn];    // 2048 B
    __shared__ float accb[4][Dn];                   // 1024 B
    __shared__ float ssb[Hn], gsb[Hn];              // 64 B

    // Prologue: issue tile-0 e loads first (longest latency)
    float4 st[4];
    {
        const float4* ep = (const float4*)(e + ((size_t)bq * Nn + tp * 2 * TR) * Dn);
#pragma unroll
        for (int j = 0; j < 4; ++j) st[j] = ep[j * 256 + t];
    }

    // Weights (L2-hot). We/Wg (D,H) -> [h][d]; Oe (H,D) copy.
    for (int i = t; i < Dn * Hn; i += 256) {
        const int d = i >> 3, h = i & 7;
        we_s[h][d] = WeG[i];
        wg_s[h][d] = WgG[i];
        ((float*)oe_s)[i] = OeG[i];
    }

    // Q for this wave's head-pair (wave-uniform)
    float4 q0, q1, q2, q3;
    {
        const float4* qp = (const float4*)(Qw + (size_t)bq * Dn + w * 16);
        q0 = qp[0]; q1 = qp[1]; q2 = qp[2]; q3 = qp[3];
    }

    const float qscale = 0.35355339059327373f;  // 1/sqrt(8)
    float acc = 0.f;                            // PV accumulator (col l)
    float sacc0 = 0.f, sacc1 = 0.f;             // exp-sums (lane 0 valid)
    float gacc0 = 0.f, gacc1 = 0.f;             // gate-sums (lane 0 valid)

#pragma unroll
    for (int it = 0; it < 2; ++it) {
        const int m0 = (tp * 2 + it) * TR;

        // [A] staged regs -> swizzled LDS: chunk (r,g) -> slot (r, g^(r&15))
#pragma unroll
        for (int j = 0; j < 4; ++j) {
            const int c = j * 256 + t, r = c >> 4, g = c & 15;
            *(float4*)&e_tile[r * Dn + ((g ^ (r & 15)) << 2)] = st[j];
        }
        __syncthreads();   // bar1: tile visible (and weights, first iter);
                           // also fences prev D's ehat reads vs C's writes

        // [B] issue next tile's loads: fly under this tile's compute
        if (it == 0) {
            const float4* ep = (const float4*)(e + ((size_t)bq * Nn + m0 + TR) * Dn);
#pragma unroll
            for (int j = 0; j < 4; ++j) st[j] = ep[j * 256 + t];
        }

        // K slice for (row l, head-pair w) — L2-hot, hidden under dots
        const float4* kp = (const float4*)(Kw + ((size_t)b * Nn + m0 + l) * Dn + w * 16);
        const float4 k0 = kp[0], k1 = kp[1], k2 = kp[2], k3 = kp[3];

        // [C] eb/gg dots: lane = row l, weights broadcast from LDS
        float eb0 = 0.f, eb1 = 0.f, gg0 = 0.f, gg1 = 0.f;
        {
            const float4* we0 = (const float4*)we_s[2 * w];
            const float4* we1 = (const float4*)we_s[2 * w + 1];
            const float4* wg0 = (const float4*)wg_s[2 * w];
            const float4* wg1 = (const float4*)wg_s[2 * w + 1];
#pragma unroll
            for (int d4 = 0; d4 < 16; ++d4) {
                const float4 e4 = *(const float4*)&e_tile[l * Dn + ((d4 ^ (l & 15)) << 2)];
                const float4 A0 = we0[d4], A1 = we1[d4];
                const float4 G0 = wg0[d4], G1 = wg1[d4];
                eb0 = fmaf(e4.x, A0.x, fmaf(e4.y, A0.y, fmaf(e4.z, A0.z, fmaf(e4.w, A0.w, eb0))));
                eb1 = fmaf(e4.x, A1.x, fmaf(e4.y, A1.y, fmaf(e4.z, A1.z, fmaf(e4.w, A1.w, eb1))));
                gg0 = fmaf(e4.x, G0.x, fmaf(e4.y, G0.y, fmaf(e4.z, G0.z, fmaf(e4.w, G0.w, gg0))));
                gg1 = fmaf(e4.x, G1.x, fmaf(e4.y, G1.y, fmaf(e4.z, G1.z, fmaf(e4.w, G1.w, gg1))));
            }
        }

        // A_qk for the 2 heads, clipped; ehat -> LDS; exp/gate wave-reduce
        {
            float a0 = k0.x*q0.x + k0.y*q0.y + k0.z*q0.z + k0.w*q0.w
                     + k1.x*q1.x + k1.y*q1.y + k1.z*q1.z + k1.w*q1.w;
            float a1 = k2.x*q2.x + k2.y*q2.y + k2.z*q2.z + k2.w*q2.w
                     + k3.x*q3.x + k3.y*q3.y + k3.z*q3.z + k3.w*q3.w;
            a0 = fminf(fmaxf(a0 * qscale, -5.f), 5.f);
            a1 = fminf(fmaxf(a1 * qscale, -5.f), 5.f);
            const float eh0 = a0 + eb0, eh1 = a1 + eb1;
            ehat_s[(2 * w) * PS + l]     = eh0;
            ehat_s[(2 * w + 1) * PS + l] = eh1;
            float p0 = __expf(eh0), p1 = __expf(eh1);
            float g0 = 1.f / (1.f + __expf(-gg0));
            float g1 = 1.f / (1.f + __expf(-gg1));
#pragma unroll
            for (int off = 32; off > 0; off >>= 1) {
                p0 += __shfl_xor(p0, off, 64);
                p1 += __shfl_xor(p1, off, 64);
                g0 += __shfl_xor(g0, off, 64);
                g1 += __shfl_xor(g1, off, 64);
            }
            sacc0 += p0; sacc1 += p1;
            gacc0 += g0; gacc1 += g1;
        }
        __syncthreads();   // bar2: ehat complete; e_tile reads done

        // [D] e_out: thread owns chunk c -> row r, colgroup cc; nt stores
        {
            float4* eo = (float4*)(eout + ((size_t)bq * Nn + m0) * Dn);
#pragma unroll
            for (int j = 0; j < 4; ++j) {
                const int c = j * 256 + t, r = c >> 4, cc = c & 15;
                f32x4 o = {0.f, 0.f, 0.f, 0.f};
#pragma unroll
                for (int ho = 0; ho < Hn; ++ho) {
                    const float ehv = ehat_s[ho * PS + r];
                    const float4 w4 = *(const float4*)&oe_s[ho][cc * 4];
                    o.x = fmaf(ehv, w4.x, o.x);
                    o.y = fmaf(ehv, w4.y, o.y);
                    o.z = fmaf(ehv, w4.z, o.z);
                    o.w = fmaf(ehv, w4.w, o.w);
                }
                __builtin_nontemporal_store(o, (f32x4*)eo + c);
            }
        }

        // PV accumulate: wave w covers rows w*16..w*16+15; p = exp(ehat)
        {
            const int hc = l >> 3;
            const float* vb = Vw + ((size_t)b * Nn + m0 + w * 16) * Dn;
#pragma unroll
            for (int i = 0; i < 16; ++i) {
                const float p = __expf(ehat_s[hc * PS + w * 16 + i]);
                acc = fmaf(p, vb[i * Dn + l], acc);
            }
        }
        // next iter's [A] may overwrite e_tile right away: [D] never reads
        // e_tile, and bar1 fences ehat_s before [C] rewrites it.
    }

    // Epilogue: fold 4 waves, emit one 80-float partial per block
    accb[w][l] = acc;
    if (l == 0) {
        ssb[2 * w] = sacc0; ssb[2 * w + 1] = sacc1;
        gsb[2 * w] = gacc0; gsb[2 * w + 1] = gacc1;
    }
    __syncthreads();
    if (w == 0) {
        const float O = accb[0][l] + accb[1][l] + accb[2][l] + accb[3][l];
        float* pb = part + (size_t)bid * PART;
        pb[l] = O;
        if (l < 8) { pb[64 + l] = ssb[l]; pb[72 + l] = gsb[l]; }
    }
}

// ---------------- Kernel 3: fold partials -> n_out ------------------------
__global__ __launch_bounds__(64) void reduce_kernel(
    const float* __restrict__ part, const float* __restrict__ WoG,
    float* __restrict__ nout)
{
    const int bq = blockIdx.x;
    const int l  = threadIdx.x;
    const int h  = l >> 3;
    const float* pb = part + (size_t)bq * NP * PART;
    float O = 0.f, S = 0.f, G = 0.f;
#pragma unroll
    for (int tl = 0; tl < NP; ++tl) {
        O += pb[tl * PART + l];
        S += pb[tl * PART + 64 + h];
        G += pb[tl * PART + 72 + h];
    }
    __shared__ float vo_s[Dn];
    vo_s[l] = (O / S) * log1pf(G);
    __syncthreads();
    float a = 0.f;
#pragma unroll
    for (int k = 0; k < Dn; ++k)
        a = fmaf(vo_s[k], WoG[k * Dn + l], a);
    nout[(size_t)bq * Dn + l] = a;
}

// ---------------- Host launcher -------------------------------------------
extern "C" void kernel_launch(void* const* d_in, const int* in_sizes, int n_in,
                              void* d_out, int out_size, void* d_ws, size_t ws_size,
                              hipStream_t stream)
{
    (void)in_sizes; (void)n_in; (void)out_size; (void)ws_size;
    const float* nin = (const float*)d_in[0];
    const float* e   = (const float*)d_in[1];
    const float* Wq  = (const float*)d_in[2];
    const float* Wk  = (const float*)d_in[3];
    const float* Wv  = (const float*)d_in[4];
    const float* Wo  = (const float*)d_in[5];
    const float* Wg  = (const float*)d_in[6];
    const float* We  = (const float*)d_in[7];
    const float* Oe  = (const float*)d_in[8];

    float* Qw   = (float*)d_ws;               // B*N*D floats
    float* Kw   = Qw + Bn * Nn * Dn;
    float* Vw   = Kw + Bn * Nn * Dn;
    float* part = Vw + Bn * Nn * Dn;          // B*N*NP*PART floats (2.6 MB)

    float* nout = (float*)d_out;              // B*N*D floats
    float* eout = nout + Bn * Nn * Dn;        // B*N*N*D floats

    qkv_kernel<<<Bn * Nn, 64, 0, stream>>>(nin, Wq, Wk, Wv, Qw, Kw, Vw);
    stream_kernel<<<Bn * Nn * NP, 256, 0, stream>>>(e, Qw, Kw, Vw, We, Wg, Oe,
                                                    eout, part);
    reduce_kernel<<<Bn * Nn, 64, 0, stream>>>(part, Wo, nout);
}

// Round 10
// 139.755 us; speedup vs baseline: 2.2620x; 2.2620x over previous
//
#include <hip/hip_runtime.h>
#include <math.h>

#define Bn 4
#define Nn 512
#define Dn 64
#define Hn 8
#define TR 64          // rows per tile-block
#define NT (Nn / TR)   // 8 tiles per (b,q)
#define PS 68          // ehat row stride (words); 8 heads -> 8 distinct banks
#define PART 80        // partial floats per block: 64 PV + 8 expsum + 8 gsum

typedef float f32x4 __attribute__((ext_vector_type(4)));

// ---------------- Kernel 1: QKV projection -------------------------------
__global__ __launch_bounds__(64) void qkv_kernel(
    const float* __restrict__ nin, const float* __restrict__ Wq,
    const float* __restrict__ Wk, const float* __restrict__ Wv,
    float* __restrict__ Qw, float* __restrict__ Kw, float* __restrict__ Vw)
{
    const int row = blockIdx.x;   // 0 .. B*N-1
    const int d = threadIdx.x;    // 0 .. 63
    __shared__ float nrow[Dn];
    nrow[d] = nin[row * Dn + d];
    __syncthreads();
    float aq = 0.f, ak = 0.f, av = 0.f;
#pragma unroll
    for (int k = 0; k < Dn; ++k) {
        const float nv = nrow[k];
        aq = fmaf(nv, Wq[k * Dn + d], aq);
        ak = fmaf(nv, Wk[k * Dn + d], ak);
        av = fmaf(nv, Wv[k * Dn + d], av);
    }
    Qw[row * Dn + d] = aq;
    Kw[row * Dn + d] = ak;
    Vw[row * Dn + d] = av;
}

// ---------------- Kernel 2: streaming tile kernel -------------------------
// One block per (b,q,tile): 64 m-rows. Coalesced 16KB e-read -> XOR-swizzled
// LDS tile -> eb/gg/A/ehat (wave = head-pair, lane = row) -> e_out per-
// output-chunk with CACHED stores (L2 merges the 16B pieces into full lines
// and writes back whole; R9 proved nt stores bypass this merge -> 3x write
// amplification + RMW fetches) -> PV/expsum/gsum partial to workspace.
__global__ __launch_bounds__(256, 6) void stream_kernel(
    const float* __restrict__ e,
    const float* __restrict__ Qw, const float* __restrict__ Kw,
    const float* __restrict__ Vw,
    const float* __restrict__ WeG, const float* __restrict__ WgG,
    const float* __restrict__ OeG,
    float* __restrict__ eout, float* __restrict__ part)
{
    const int bid  = blockIdx.x;        // bq*NT + tile
    const int bq   = bid >> 3;          // NT = 8
    const int tile = bid & 7;
    const int b    = bq >> 9;           // N = 512
    const int m0   = tile * TR;
    const int t    = threadIdx.x;       // 0..255
    const int w    = t >> 6;            // wave 0..3 = head-pair {2w,2w+1}
    const int l    = t & 63;            // lane 0..63 = row within tile

    __shared__ float e_tile[TR * Dn];               // 16384 B, swizzled groups
    __shared__ float ehat_s[Hn * PS];               // 2176 B
    __shared__ __align__(16) float we_s[Hn][Dn];    // [h][d]  2048 B
    __shared__ __align__(16) float wg_s[Hn][Dn];    // 2048 B
    __shared__ __align__(16) float oe_s[Hn][Dn];    // 2048 B
    __shared__ float accb[4][Dn];                   // 1024 B
    __shared__ float ssb[Hn], gsb[Hn];              // 64 B

    // 1) e-tile loads first (HBM latency): 16KB contiguous, 4 float4/thread
    float4 st[4];
    {
        const float4* ep = (const float4*)(e + ((size_t)bq * Nn + m0) * Dn);
#pragma unroll
        for (int j = 0; j < 4; ++j) st[j] = ep[j * 256 + t];
    }

    // 2) K slice for this wave's head-pair (L2-hot) + Q (wave-uniform)
    float a0, a1;
    {
        const float4* kp = (const float4*)(Kw + ((size_t)b * Nn + m0 + l) * Dn + w * 16);
        const float4 k0 = kp[0], k1 = kp[1], k2 = kp[2], k3 = kp[3];
        const float4* qp = (const float4*)(Qw + (size_t)bq * Dn + w * 16);
        const float4 q0 = qp[0], q1 = qp[1], q2 = qp[2], q3 = qp[3];
        const float qscale = 0.35355339059327373f;  // 1/sqrt(8)
        a0 = k0.x*q0.x + k0.y*q0.y + k0.z*q0.z + k0.w*q0.w
           + k1.x*q1.x + k1.y*q1.y + k1.z*q1.z + k1.w*q1.w;
        a1 = k2.x*q2.x + k2.y*q2.y + k2.z*q2.z + k2.w*q2.w
           + k3.x*q3.x + k3.y*q3.y + k3.z*q3.z + k3.w*q3.w;
        a0 = fminf(fmaxf(a0 * qscale, -5.f), 5.f);
        a1 = fminf(fmaxf(a1 * qscale, -5.f), 5.f);
    }

    // 3) weights (L2-hot). We/Wg (D,H) -> [h][d]; Oe (H,D) copy.
    for (int i = t; i < Dn * Hn; i += 256) {
        const int d = i >> 3, h = i & 7;
        we_s[h][d] = WeG[i];
        wg_s[h][d] = WgG[i];
        ((float*)oe_s)[i] = OeG[i];
    }

    // 4) staged e -> swizzled LDS: chunk (r,g) -> slot (r, g^(r&15))
#pragma unroll
    for (int j = 0; j < 4; ++j) {
        const int c = j * 256 + t, r = c >> 4, g = c & 15;
        *(float4*)&e_tile[r * Dn + ((g ^ (r & 15)) << 2)] = st[j];
    }
    __syncthreads();

    // 5) eb/gg dots: lane = row l, read slot (l, d4^(l&15)) = global (l, d4)
    float eb0 = 0.f, eb1 = 0.f, gg0 = 0.f, gg1 = 0.f;
    {
        const float4* we0 = (const float4*)we_s[2 * w];
        const float4* we1 = (const float4*)we_s[2 * w + 1];
        const float4* wg0 = (const float4*)wg_s[2 * w];
        const float4* wg1 = (const float4*)wg_s[2 * w + 1];
#pragma unroll
        for (int d4 = 0; d4 < 16; ++d4) {
            const float4 e4 = *(const float4*)&e_tile[l * Dn + (((d4 ^ (l & 15))) << 2)];
            const float4 A0 = we0[d4], A1 = we1[d4];
            const float4 G0 = wg0[d4], G1 = wg1[d4];
            eb0 = fmaf(e4.x, A0.x, fmaf(e4.y, A0.y, fmaf(e4.z, A0.z, fmaf(e4.w, A0.w, eb0))));
            eb1 = fmaf(e4.x, A1.x, fmaf(e4.y, A1.y, fmaf(e4.z, A1.z, fmaf(e4.w, A1.w, eb1))));
            gg0 = fmaf(e4.x, G0.x, fmaf(e4.y, G0.y, fmaf(e4.z, G0.z, fmaf(e4.w, G0.w, gg0))));
            gg1 = fmaf(e4.x, G1.x, fmaf(e4.y, G1.y, fmaf(e4.z, G1.z, fmaf(e4.w, G1.w, gg1))));
        }
    }

    // 6) ehat -> LDS; per-head exp-sum and sigmoid-sum via wave shuffle
    {
        const float eh0 = a0 + eb0, eh1 = a1 + eb1;
        ehat_s[(2 * w) * PS + l]     = eh0;
        ehat_s[(2 * w + 1) * PS + l] = eh1;
        float p0 = __expf(eh0), p1 = __expf(eh1);
        float g0 = 1.f / (1.f + __expf(-gg0));
        float g1 = 1.f / (1.f + __expf(-gg1));
#pragma unroll
        for (int off = 32; off > 0; off >>= 1) {
            p0 += __shfl_xor(p0, off, 64);
            p1 += __shfl_xor(p1, off, 64);
            g0 += __shfl_xor(g0, off, 64);
            g1 += __shfl_xor(g1, off, 64);
        }
        if (l == 0) {
            ssb[2 * w] = p0; ssb[2 * w + 1] = p1;
            gsb[2 * w] = g0; gsb[2 * w + 1] = g1;
        }
    }
    __syncthreads();   // ehat/ssb/gsb ready; eb-phase done with e_tile

    // 7) e_out: thread owns chunk c -> row r, colgroup cc; ehat via LDS
    //    broadcast; CACHED stores (full-line merge happens in L2)
    {
        float4* eo = (float4*)(eout + ((size_t)bq * Nn + m0) * Dn);
#pragma unroll
        for (int j = 0; j < 4; ++j) {
            const int c = j * 256 + t, r = c >> 4, cc = c & 15;
            f32x4 o = {0.f, 0.f, 0.f, 0.f};
#pragma unroll
            for (int ho = 0; ho < Hn; ++ho) {
                const float ehv = ehat_s[ho * PS + r];
                const float4 w4 = *(const float4*)&oe_s[ho][cc * 4];
                o.x = fmaf(ehv, w4.x, o.x);
                o.y = fmaf(ehv, w4.y, o.y);
                o.z = fmaf(ehv, w4.z, o.z);
                o.w = fmaf(ehv, w4.w, o.w);
            }
            *((f32x4*)eo + c) = o;
        }
    }

    // 8) PV partials: wave w covers rows w*16..w*16+15; p = exp(ehat)
    {
        const int h = l >> 3;
        float acc = 0.f;
        const float* vrow = Vw + ((size_t)b * Nn + m0 + w * 16) * Dn;
#pragma unroll
        for (int i = 0; i < 16; ++i) {
            const float p = __expf(ehat_s[h * PS + w * 16 + i]);
            acc = fmaf(p, vrow[i * Dn + l], acc);
        }
        accb[w][l] = acc;
    }
    __syncthreads();

    // 9) fold 4 waves, emit 80-float partial
    if (w == 0) {
        const float O = accb[0][l] + accb[1][l] + accb[2][l] + accb[3][l];
        float* pb = part + (size_t)bid * PART;
        pb[l] = O;
        if (l < 8) { pb[64 + l] = ssb[l]; pb[72 + l] = gsb[l]; }
    }
}

// ---------------- Kernel 3: fold partials -> n_out ------------------------
__global__ __launch_bounds__(64) void reduce_kernel(
    const float* __restrict__ part, const float* __restrict__ WoG,
    float* __restrict__ nout)
{
    const int bq = blockIdx.x;
    const int l  = threadIdx.x;
    const int h  = l >> 3;
    const float* pb = part + (size_t)bq * NT * PART;
    float O = 0.f, S = 0.f, G = 0.f;
#pragma unroll
    for (int tl = 0; tl < NT; ++tl) {
        O += pb[tl * PART + l];
        S += pb[tl * PART + 64 + h];
        G += pb[tl * PART + 72 + h];
    }
    __shared__ float vo_s[Dn];
    vo_s[l] = (O / S) * log1pf(G);
    __syncthreads();
    float a = 0.f;
#pragma unroll
    for (int k = 0; k < Dn; ++k)
        a = fmaf(vo_s[k], WoG[k * Dn + l], a);
    nout[(size_t)bq * Dn + l] = a;
}

// ---------------- Host launcher -------------------------------------------
extern "C" void kernel_launch(void* const* d_in, const int* in_sizes, int n_in,
                              void* d_out, int out_size, void* d_ws, size_t ws_size,
                              hipStream_t stream)
{
    (void)in_sizes; (void)n_in; (void)out_size; (void)ws_size;
    const float* nin = (const float*)d_in[0];
    const float* e   = (const float*)d_in[1];
    const float* Wq  = (const float*)d_in[2];
    const float* Wk  = (const float*)d_in[3];
    const float* Wv  = (const float*)d_in[4];
    const float* Wo  = (const float*)d_in[5];
    const float* Wg  = (const float*)d_in[6];
    const float* We  = (const float*)d_in[7];
    const float* Oe  = (const float*)d_in[8];

    float* Qw   = (float*)d_ws;               // B*N*D floats
    float* Kw   = Qw + Bn * Nn * Dn;
    float* Vw   = Kw + Bn * Nn * Dn;
    float* part = Vw + Bn * Nn * Dn;          // B*N*NT*PART floats (5.2 MB)

    float* nout = (float*)d_out;              // B*N*D floats
    float* eout = nout + Bn * Nn * Dn;        // B*N*N*D floats

    qkv_kernel<<<Bn * Nn, 64, 0, stream>>>(nin, Wq, Wk, Wv, Qw, Kw, Vw);
    stream_kernel<<<Bn * Nn * NT, 256, 0, stream>>>(e, Qw, Kw, Vw, We, Wg, Oe,
                                                    eout, part);
    reduce_kernel<<<Bn * Nn, 64, 0, stream>>>(part, Wo, nout);
}